// Round 2
// baseline (1587.457 us; speedup 1.0000x reference)
//
#include <hip/hip_runtime.h>
#include <hip/hip_fp16.h>
#include <math.h>

// ---------------------------------------------------------------------------
// Mamba2 stereo SSD block. fp32 compute, fp16 intermediate storage.
// B=4, L=8192 (64x128), D_MODEL=256, D_INNER=512, NHEADS=4, HEADDIM=128,
// D_STATE=64, CONV_DIM=640, CHUNK=128, NCHUNK=64.
//
// Workspace map (bytes from d_ws base), total 254,803,968 (= 243 MiB):
//   F      fp32 [65536,256]       [0,          67,108,864)   live: ds -> z-gemm
//   xbcR   fp16 [32768,640]       [67,108,864, 109,051,904)  live: gemm -> ssd_c
//   XC     fp16 [32768,640]       [109,051,904,150,994,944)  live: conv -> ssd_c
//   ybuf   fp16 [65536,512]       [150,994,944,218,103,808)  live: ssd_a -> out gemm
//     xbcL fp16 [32768,640] alias [150,994,944,192,937,984)  live: gemm -> conv
//   states fp16 [8,64,4,128,64]   [218,103,808,251,658,240)  live: ssd_a -> ssd_c
//   dtbuf  fp32 [8,4,8192]        [251,658,240,252,706,816)
//   esbuf  fp32 [8,4,8192]        [252,706,816,253,755,392)
//   cumbuf fp32 [8,4,8192]        [253,755,392,254,803,968)
//   zbuf   fp16 [65536,512] alias [67,108,864, 134,217,728)  (over dead xbcR+XC)
// All kernels use <= 64 KB LDS.
// ---------------------------------------------------------------------------

__device__ __forceinline__ float siluf(float v) { return v / (1.0f + expf(-v)); }

// ---------------- downsample: 4x4/4 conv, 3->256 ch, NCHW -> (row, c) -------
__global__ __launch_bounds__(256) void k_downsample(
    const float* __restrict__ limg, const float* __restrict__ rimg,
    const float* __restrict__ w, const float* __restrict__ bias,
    float* __restrict__ F)
{
    __shared__ float wS[12288];   // [c][48]
    __shared__ float pS[768];     // [pix][48]
    int t = threadIdx.x;
    int bid = blockIdx.x;               // og(8) | oy(64) | b(4) | side(2)
    int og = bid & 7;
    int oy = (bid >> 3) & 63;
    int b  = (bid >> 9) & 3;
    int side = bid >> 11;
    const float* img = side ? rimg : limg;

    for (int e = t * 4; e < 12288; e += 1024)
        *(float4*)(wS + e) = *(const float4*)(w + e);

    int ox0 = og * 16;
    for (int f = t; f < 768; f += 256) {
        int kx = f & 3, pix = (f >> 2) & 15, ky = (f >> 6) & 3, ci = f >> 8;
        float v = img[((b * 3 + ci) * 256 + oy * 4 + ky) * 512 + ox0 * 4 + pix * 4 + kx];
        pS[pix * 48 + ci * 16 + ky * 4 + kx] = v;
    }
    __syncthreads();

    int c = t;
    float wreg[48];
#pragma unroll
    for (int q = 0; q < 12; q++) {
        float4 v = *(const float4*)(wS + c * 48 + q * 4);
        wreg[q * 4 + 0] = v.x; wreg[q * 4 + 1] = v.y;
        wreg[q * 4 + 2] = v.z; wreg[q * 4 + 3] = v.w;
    }
    float bv = bias[c];
    long base = ((long)(side * 32768 + b * 8192 + oy * 128 + ox0)) * 256 + c;
    for (int pix = 0; pix < 16; pix++) {
        float acc = bv;
#pragma unroll
        for (int q = 0; q < 12; q++) {
            float4 p4 = *(const float4*)(pS + pix * 48 + q * 4);
            acc += wreg[q * 4 + 0] * p4.x + wreg[q * 4 + 1] * p4.y
                 + wreg[q * 4 + 2] * p4.z + wreg[q * 4 + 3] * p4.w;
        }
        F[base + (long)pix * 256] = acc;
    }
}

// ------- fp32 x fp32 -> fp16 NT GEMM, 64x64 tile; rows < 32768 go to CL ----
__global__ __launch_bounds__(256) void k_gemm_f32_f16(
    const float* __restrict__ A, const float* __restrict__ B,
    __half* __restrict__ CL, __half* __restrict__ CR, int K, int ldc)
{
    __shared__ float At[64][68];   // [k][m]
    __shared__ float Bt[64][68];   // [k][n]
    int tx = threadIdx.x, ty = threadIdx.y;
    int t = ty * 16 + tx;
    long m0 = (long)blockIdx.x * 64;
    int n0 = blockIdx.y * 64;
    float acc[4][4] = {};

    for (int kk = 0; kk < K; kk += 64) {
#pragma unroll
        for (int r = 0; r < 4; r++) {
            int f4 = r * 256 + t; int row = f4 >> 4; int k4 = (f4 & 15) * 4;
            float4 v = *(const float4*)(A + (m0 + row) * K + kk + k4);
            At[k4 + 0][row] = v.x; At[k4 + 1][row] = v.y;
            At[k4 + 2][row] = v.z; At[k4 + 3][row] = v.w;
        }
#pragma unroll
        for (int r = 0; r < 4; r++) {
            int f4 = r * 256 + t; int row = f4 >> 4; int k4 = (f4 & 15) * 4;
            float4 v = *(const float4*)(B + (long)(n0 + row) * K + kk + k4);
            Bt[k4 + 0][row] = v.x; Bt[k4 + 1][row] = v.y;
            Bt[k4 + 2][row] = v.z; Bt[k4 + 3][row] = v.w;
        }
        __syncthreads();
#pragma unroll 16
        for (int k = 0; k < 64; k++) {
            float4 a4 = *(const float4*)&At[k][ty * 4];
            float4 b4 = *(const float4*)&Bt[k][tx * 4];
            float av[4] = {a4.x, a4.y, a4.z, a4.w};
            float bv[4] = {b4.x, b4.y, b4.z, b4.w};
#pragma unroll
            for (int i = 0; i < 4; i++)
#pragma unroll
                for (int j = 0; j < 4; j++)
                    acc[i][j] += av[i] * bv[j];
        }
        __syncthreads();
    }
    __half* Cbase = (m0 < 32768) ? CL + m0 * ldc : CR + (m0 - 32768) * ldc;
#pragma unroll
    for (int i = 0; i < 4; i++) {
        __half2* p = (__half2*)(Cbase + (long)(ty * 4 + i) * ldc + n0 + tx * 4);
        p[0] = __floats2half2_rn(acc[i][0], acc[i][1]);
        p[1] = __floats2half2_rn(acc[i][2], acc[i][3]);
    }
}

// ------- fp16 x fp32 -> fp32 NT GEMM (out_proj) ----------------------------
__global__ __launch_bounds__(256) void k_gemm_f16_f32(
    const __half* __restrict__ A, const float* __restrict__ B,
    float* __restrict__ C, int K, int ldc)
{
    __shared__ float At[64][68];
    __shared__ float Bt[64][68];
    int tx = threadIdx.x, ty = threadIdx.y;
    int t = ty * 16 + tx;
    long m0 = (long)blockIdx.x * 64;
    int n0 = blockIdx.y * 64;
    float acc[4][4] = {};

    for (int kk = 0; kk < K; kk += 64) {
#pragma unroll
        for (int r = 0; r < 4; r++) {
            int f4 = r * 256 + t; int row = f4 >> 4; int k4 = (f4 & 15) * 4;
            const __half2* ap = (const __half2*)(A + (m0 + row) * K + kk + k4);
            float2 u = __half22float2(ap[0]);
            float2 v = __half22float2(ap[1]);
            At[k4 + 0][row] = u.x; At[k4 + 1][row] = u.y;
            At[k4 + 2][row] = v.x; At[k4 + 3][row] = v.y;
        }
#pragma unroll
        for (int r = 0; r < 4; r++) {
            int f4 = r * 256 + t; int row = f4 >> 4; int k4 = (f4 & 15) * 4;
            float4 v = *(const float4*)(B + (long)(n0 + row) * K + kk + k4);
            Bt[k4 + 0][row] = v.x; Bt[k4 + 1][row] = v.y;
            Bt[k4 + 2][row] = v.z; Bt[k4 + 3][row] = v.w;
        }
        __syncthreads();
#pragma unroll 16
        for (int k = 0; k < 64; k++) {
            float4 a4 = *(const float4*)&At[k][ty * 4];
            float4 b4 = *(const float4*)&Bt[k][tx * 4];
            float av[4] = {a4.x, a4.y, a4.z, a4.w};
            float bv[4] = {b4.x, b4.y, b4.z, b4.w};
#pragma unroll
            for (int i = 0; i < 4; i++)
#pragma unroll
                for (int j = 0; j < 4; j++)
                    acc[i][j] += av[i] * bv[j];
        }
        __syncthreads();
    }
#pragma unroll
    for (int i = 0; i < 4; i++) {
        float4 v = make_float4(acc[i][0], acc[i][1], acc[i][2], acc[i][3]);
        *(float4*)(C + (m0 + ty * 4 + i) * ldc + n0 + tx * 4) = v;
    }
}

// ---------------- dt: fp32 dot of F row with W rows 1152..1155, softplus ----
__global__ __launch_bounds__(256) void k_dt(
    const float* __restrict__ F, const float* __restrict__ W,
    const float* __restrict__ dt_bias, float* __restrict__ dtbuf)
{
    int t = threadIdx.x;
    int wv = t >> 6, lane = t & 63;
    long m = (long)blockIdx.x * 4 + wv;     // 0..65535
    float4 fv = *(const float4*)(F + m * 256 + lane * 4);
    float dots[4];
#pragma unroll
    for (int h = 0; h < 4; h++) {
        float4 w4 = *(const float4*)(W + (long)(1152 + h) * 256 + lane * 4);
        float d = fv.x * w4.x + fv.y * w4.y + fv.z * w4.z + fv.w * w4.w;
#pragma unroll
        for (int off = 32; off; off >>= 1) d += __shfl_down(d, off, 64);
        dots[h] = d;
    }
    if (lane == 0) {
        long sb = m >> 13;                  // side*4 + b
        long l = m & 8191;
#pragma unroll
        for (int h = 0; h < 4; h++) {
            float v = dots[h] + dt_bias[h];
            float sp = (v > 20.0f) ? v : log1pf(expf(v));
            dtbuf[(sb * 4 + h) * 8192 + l] = sp;
        }
    }
}

// ---------------- per-chunk cumsum of dt*A and per-step decay exp(dt*A) -----
__global__ __launch_bounds__(256) void k_cum(
    const float* __restrict__ dtbuf, const float* __restrict__ A_log,
    float* __restrict__ cumbuf, float* __restrict__ esbuf)
{
    int g = blockIdx.x * 256 + threadIdx.x;     // 2048 = sb(8)*h(4)*c(64)
    if (g >= 2048) return;
    int c = g & 63, h = (g >> 6) & 3, sb = g >> 8;
    float A = -expf(A_log[h]);
    long base = ((long)sb * 4 + h) * 8192 + c * 128;
    float run = 0.f;
    for (int i = 0; i < 128; i++) {
        float a = dtbuf[base + i] * A;
        run += a;
        cumbuf[base + i] = run;
        esbuf[base + i] = expf(a);
    }
}

// ---------------- causal depthwise conv1d (k=4) + bias + silu, left only ----
__global__ __launch_bounds__(256) void k_conv1d(
    const __half* __restrict__ xbcL, const float* __restrict__ cw,
    const float* __restrict__ cb, __half* __restrict__ XC)
{
    long idx = (long)blockIdx.x * 256 + threadIdx.x;    // 32768*640
    if (idx >= (long)32768 * 640) return;
    int cc = (int)(idx % 640);
    long row = idx / 640;
    int l = (int)(row & 8191);
    float acc = cb[cc];
#pragma unroll
    for (int k = 0; k < 4; k++) {
        int j = l - 3 + k;
        if (j >= 0) acc += cw[cc * 4 + k] * __half2float(xbcL[(row - 3 + k) * 640 + cc]);
    }
    XC[row * 640 + cc] = __float2half(siluf(acc));
}

// ---------------- SSD phase A: per-(side,b,chunk,head) recurrence -----------
// LDS: Bs (dt-folded) [128][64] fp32 + Cs [128][64] fp32 = 65536 B exactly.
__global__ __launch_bounds__(256) void k_ssd_a(
    const __half* __restrict__ xbcR, const __half* __restrict__ XC,
    const float* __restrict__ dtbuf, const float* __restrict__ esbuf,
    const float* __restrict__ Dvec, __half* __restrict__ ybuf,
    __half* __restrict__ states)
{
    extern __shared__ float sm[];
    float* Bs = sm;            // [i=128][n=64], pre-multiplied by dt_i
    float* Cs = sm + 8192;     // [i=128][n=64]

    int t = threadIdx.x;
    int bid = blockIdx.x;
    int side = bid >> 10;
    int rem = bid & 1023;
    int b = rem >> 8, c = (rem >> 2) & 63, h = rem & 3;
    long l0 = (long)b * 8192 + c * 128;

    const __half *xsrc, *Bsrc, *Csrc;
    if (side == 0) { xsrc = xbcR; Bsrc = xbcR + 512; Csrc = XC + 576; }
    else           { xsrc = XC;   Bsrc = XC + 512;   Csrc = xbcR + 576; }

    long dtbase = ((long)(side * 4 + b) * 4 + h) * 8192 + c * 128;

    for (int e = t * 4; e < 8192; e += 1024) {
        int i = e >> 6, n = e & 63;
        float dti = dtbuf[dtbase + i];
        const __half2* bp = (const __half2*)(Bsrc + (l0 + i) * 640 + n);
        float2 b0 = __half22float2(bp[0]), b1 = __half22float2(bp[1]);
        Bs[e + 0] = dti * b0.x; Bs[e + 1] = dti * b0.y;
        Bs[e + 2] = dti * b1.x; Bs[e + 3] = dti * b1.y;
        const __half2* cp = (const __half2*)(Csrc + (l0 + i) * 640 + n);
        float2 c0 = __half22float2(cp[0]), c1 = __half22float2(cp[1]);
        Cs[e + 0] = c0.x; Cs[e + 1] = c0.y; Cs[e + 2] = c1.x; Cs[e + 3] = c1.y;
    }
    __syncthreads();

    int nh = t & 1;
    int p = t >> 1;
    float hreg[32];
#pragma unroll
    for (int q = 0; q < 32; q++) hreg[q] = 0.f;
    float Dh = Dvec[h];
    const __half* xcol = xsrc + l0 * 640 + h * 128 + p;
    long ybase = ((long)side * 32768 + l0) * 512 + h * 128 + p;

    for (int i = 0; i < 128; i++) {
        float dec = esbuf[dtbase + i];
        float xv = __half2float(xcol[(long)i * 640]);
        const float* brow = Bs + i * 64 + nh * 32;
        const float* crow = Cs + i * 64 + nh * 32;
        float accp = 0.f;
#pragma unroll
        for (int q = 0; q < 8; q++) {
            float4 b4 = *(const float4*)(brow + q * 4);
            float4 c4 = *(const float4*)(crow + q * 4);
            hreg[q * 4 + 0] = dec * hreg[q * 4 + 0] + b4.x * xv;
            hreg[q * 4 + 1] = dec * hreg[q * 4 + 1] + b4.y * xv;
            hreg[q * 4 + 2] = dec * hreg[q * 4 + 2] + b4.z * xv;
            hreg[q * 4 + 3] = dec * hreg[q * 4 + 3] + b4.w * xv;
            accp += c4.x * hreg[q * 4 + 0] + c4.y * hreg[q * 4 + 1]
                  + c4.z * hreg[q * 4 + 2] + c4.w * hreg[q * 4 + 3];
        }
        accp += __shfl_xor(accp, 1, 64);
        if (nh == 0) ybuf[ybase + (long)i * 512] = __float2half(accp + Dh * xv);
    }
    // states[(side*4+b)][c][h][p][n] fp16
    long sbase = ((((long)(side * 4 + b) * 64 + c) * 4 + h) * 128 + p) * 64 + nh * 32;
    __half2* sp = (__half2*)(states + sbase);
#pragma unroll
    for (int q = 0; q < 16; q++)
        sp[q] = __floats2half2_rn(hreg[2 * q], hreg[2 * q + 1]);
}

// ---------------- inter-chunk scan over 64 chunks (in place, fp16) ----------
__global__ __launch_bounds__(256) void k_scan(
    __half* __restrict__ states, const float* __restrict__ cumbuf)
{
    long g = (long)blockIdx.x * 256 + threadIdx.x;   // 262144 threads
    int n = (int)(g & 63);
    int p = (int)((g >> 6) & 127);
    int h = (int)((g >> 13) & 3);
    int sb = (int)(g >> 15);                         // side*4+b
    long sbase = (((long)sb * 256 + h) * 128 + p) * 64 + n;   // c=0
    long cbase = ((long)sb * 4 + h) * 8192 + 127;
    float hr = 0.f;
    for (int c = 0; c < 64; c++) {
        long idx = sbase + (long)c * 32768;
        float dec = expf(cumbuf[cbase + (long)c * 128]);
        float s = __half2float(states[idx]);
        states[idx] = __float2half(hr);          // hprev for chunk c
        hr = hr * dec + s;
    }
}

// ---------------- SSD phase C: y += exp(cum_i) * C_i . hprev ----------------
// LDS: Ct fp16 [64][136] + Ht fp16 [64][136] = 34816 B.
__global__ __launch_bounds__(256) void k_ssd_c(
    const __half* __restrict__ xbcR, const __half* __restrict__ XC,
    const __half* __restrict__ states, const float* __restrict__ cumbuf,
    __half* __restrict__ ybuf)
{
    extern __shared__ __half smh[];
    __half* Ct = smh;                // [n=64][i=128] pad 136
    __half* Ht = smh + 64 * 136;     // [n=64][p=128] pad 136
    int tx = threadIdx.x, ty = threadIdx.y;
    int t = ty * 16 + tx;
    int bid = blockIdx.x;
    int side = bid >> 10;
    int rem = bid & 1023;
    int b = rem >> 8, c = (rem >> 2) & 63, h = rem & 3;
    long l0 = (long)b * 8192 + c * 128;

    const __half* Csrc = (side == 0) ? XC + 576 : xbcR + 576;

    for (int e = t * 4; e < 8192; e += 1024) {
        int i = e >> 6, n = e & 63;
        const __half2* cp = (const __half2*)(Csrc + (l0 + i) * 640 + n);
        __half2 c0 = cp[0], c1 = cp[1];
        Ct[(n + 0) * 136 + i] = __low2half(c0);
        Ct[(n + 1) * 136 + i] = __high2half(c0);
        Ct[(n + 2) * 136 + i] = __low2half(c1);
        Ct[(n + 3) * 136 + i] = __high2half(c1);
    }
    long sb2 = (long)side * 4 + b;
    long stile = ((sb2 * 64 + c) * 4 + h) * 8192;
    for (int e = t * 4; e < 8192; e += 1024) {
        int p = e >> 6, n = e & 63;
        const __half2* spt = (const __half2*)(states + stile + e);
        __half2 s0 = spt[0], s1 = spt[1];
        Ht[(n + 0) * 136 + p] = __low2half(s0);
        Ht[(n + 1) * 136 + p] = __high2half(s0);
        Ht[(n + 2) * 136 + p] = __low2half(s1);
        Ht[(n + 3) * 136 + p] = __high2half(s1);
    }
    __syncthreads();

    float acc[8][8] = {};
#pragma unroll 4
    for (int k = 0; k < 64; k++) {
        const __half2* cr = (const __half2*)(Ct + k * 136 + ty * 8);
        const __half2* hr = (const __half2*)(Ht + k * 136 + tx * 8);
        float av[8], bv[8];
#pragma unroll
        for (int j = 0; j < 4; j++) {
            float2 u = __half22float2(cr[j]);
            av[2 * j] = u.x; av[2 * j + 1] = u.y;
            float2 w = __half22float2(hr[j]);
            bv[2 * j] = w.x; bv[2 * j + 1] = w.y;
        }
#pragma unroll
        for (int i = 0; i < 8; i++)
#pragma unroll
            for (int j = 0; j < 8; j++)
                acc[i][j] += av[i] * bv[j];
    }
    long dtbase = (sb2 * 4 + h) * 8192 + c * 128;
    long ybase = ((long)side * 32768 + l0) * 512 + h * 128;
#pragma unroll
    for (int i = 0; i < 8; i++) {
        int ii = ty * 8 + i;
        float ex = expf(cumbuf[dtbase + ii]);
        __half2* yrow = (__half2*)(ybuf + ybase + (long)ii * 512 + tx * 8);
#pragma unroll
        for (int j = 0; j < 4; j++) {
            float2 o = __half22float2(yrow[j]);
            o.x += ex * acc[i][2 * j];
            o.y += ex * acc[i][2 * j + 1];
            yrow[j] = __floats2half2_rn(o.x, o.y);
        }
    }
}

// ---------------- gated rmsnorm: y = rmsnorm(y * silu(z)) * w  (in place) ---
__global__ __launch_bounds__(256) void k_rmsnorm(
    __half* __restrict__ ybuf, const __half* __restrict__ zbuf,
    const float* __restrict__ nw)
{
    int t = threadIdx.x;
    int wv = t >> 6, lane = t & 63;
    long r = (long)blockIdx.x * 4 + wv;
    __half2* yrow = (__half2*)(ybuf + r * 512 + lane * 8);
    const __half2* zrow = (const __half2*)(zbuf + r * 512 + lane * 8);
    float g[8];
#pragma unroll
    for (int j = 0; j < 4; j++) {
        float2 yv = __half22float2(yrow[j]);
        float2 zv = __half22float2(zrow[j]);
        g[2 * j]     = yv.x * siluf(zv.x);
        g[2 * j + 1] = yv.y * siluf(zv.y);
    }
    float ss = 0.f;
#pragma unroll
    for (int i = 0; i < 8; i++) ss += g[i] * g[i];
#pragma unroll
    for (int off = 32; off; off >>= 1) ss += __shfl_xor(ss, off, 64);
    float sc = rsqrtf(ss * (1.0f / 512.0f) + 1e-5f);
#pragma unroll
    for (int j = 0; j < 4; j++) {
        float w0 = nw[lane * 8 + 2 * j], w1 = nw[lane * 8 + 2 * j + 1];
        yrow[j] = __floats2half2_rn(g[2 * j] * sc * w0, g[2 * j + 1] * sc * w1);
    }
}

// ---------------------------------------------------------------------------
extern "C" void kernel_launch(void* const* d_in, const int* in_sizes, int n_in,
                              void* d_out, int out_size, void* d_ws, size_t ws_size,
                              hipStream_t stream)
{
    (void)in_sizes; (void)n_in; (void)out_size; (void)ws_size;
    const float* limg = (const float*)d_in[0];
    const float* rimg = (const float*)d_in[1];
    const float* dsw  = (const float*)d_in[2];
    const float* dsb  = (const float*)d_in[3];
    const float* ipw  = (const float*)d_in[4];
    const float* cw   = (const float*)d_in[5];
    const float* cb   = (const float*)d_in[6];
    const float* dtb  = (const float*)d_in[7];
    const float* alog = (const float*)d_in[8];
    const float* Dv   = (const float*)d_in[9];
    const float* nw   = (const float*)d_in[10];
    const float* opw  = (const float*)d_in[11];
    float* out = (float*)d_out;

    char* ws = (char*)d_ws;
    float*  F      = (float*) (ws + 0);
    __half* xbcR   = (__half*)(ws + 67108864);
    __half* XC     = (__half*)(ws + 109051904);
    __half* ybuf   = (__half*)(ws + 150994944);
    __half* xbcL   = ybuf;                       // alias, dead before ssd_a
    __half* states = (__half*)(ws + 218103808);
    float*  dtbuf  = (float*) (ws + 251658240);
    float*  esbuf  = (float*) (ws + 252706816);
    float*  cumbuf = (float*) (ws + 253755392);
    __half* zbuf   = (__half*)(ws + 67108864);   // alias over dead xbcR+XC

    k_downsample<<<4096, 256, 0, stream>>>(limg, rimg, dsw, dsb, F);
    // in_proj, xBC columns only (ipw rows 512..1151)
    k_gemm_f32_f16<<<dim3(1024, 10), dim3(16, 16), 0, stream>>>(
        F, ipw + 512 * 256, xbcL, xbcR, 256, 640);
    k_dt<<<16384, 256, 0, stream>>>(F, ipw, dtb, dtbuf);
    k_cum<<<8, 256, 0, stream>>>(dtbuf, alog, cumbuf, esbuf);
    k_conv1d<<<81920, 256, 0, stream>>>(xbcL, cw, cb, XC);
    k_ssd_a<<<2048, 256, 65536, stream>>>(xbcR, XC, dtbuf, esbuf, Dv, ybuf, states);
    k_scan<<<1024, 256, 0, stream>>>(states, cumbuf);
    k_ssd_c<<<2048, dim3(16, 16), 34816, stream>>>(xbcR, XC, states, cumbuf, ybuf);
    // z = F @ ipw[0:512]^T  (into region freed by xbcR/XC)
    k_gemm_f32_f16<<<dim3(1024, 8), dim3(16, 16), 0, stream>>>(
        F, ipw, zbuf, zbuf + (long)32768 * 512, 256, 512);
    k_rmsnorm<<<16384, 256, 0, stream>>>(ybuf, zbuf, nw);
    k_gemm_f16_f32<<<dim3(1024, 4), dim3(16, 16), 0, stream>>>(
        ybuf, opw, out, 512, 256);
}

// Round 3
// 848.832 us; speedup vs baseline: 1.8702x; 1.8702x over previous
//
#include <hip/hip_runtime.h>
#include <hip/hip_fp16.h>
#include <math.h>

// ---------------------------------------------------------------------------
// Mamba2 stereo SSD block. f16 MFMA GEMMs, fp32 sensitive paths (dt/cum/exp).
// B=4, L=8192 (64x128), D_MODEL=256, D_INNER=512, NHEADS=4, HEADDIM=128,
// D_STATE=64, CONV_DIM=640, CHUNK=128, NCHUNK=64.
//
// Workspace map (bytes), total 222,103,552 (~212 MiB):
//   F16    f16 [65536,256]     [0,           33,554,432)
//   ipw16  f16 [1156,256]      [33,554,432,  34,146,304)
//   opw16  f16 [256,512]       [34,146,304,  34,408,448)
//   dtbuf  f32 [8,4,8192]      [34,408,448,  35,457,024)
//   esbuf  f32 [8,4,8192]      [35,457,024,  36,505,600)
//   cumbuf f32 [8,4,8192]      [36,505,600,  37,554,176)
//   xbcR   f16 [32768,640]     [37,554,176,  79,497,216)   live: gemm -> ssd_c
//   XC     f16 [32768,640]     [79,497,216, 121,440,256)   live: conv -> ssd_c
//   ybuf   f16 [65536,512]     [121,440,256,188,549,120)   (xbcL aliases head)
//   states f16 [8,64,4,128,64] [188,549,120,222,103,552)
//   zbuf   f16 [65536,512]     alias over dead xbcR+XC
// ---------------------------------------------------------------------------

typedef _Float16 f16;
typedef __attribute__((ext_vector_type(8))) _Float16 f16x8;
typedef __attribute__((ext_vector_type(4))) _Float16 f16x4;
typedef __attribute__((ext_vector_type(4))) float f32x4;

__device__ __forceinline__ float siluf(float v) { return v / (1.0f + expf(-v)); }

__device__ __forceinline__ void gload_lds16(const void* g, void* l) {
    __builtin_amdgcn_global_load_lds(
        (const __attribute__((address_space(1))) void*)g,
        (__attribute__((address_space(3))) void*)l, 16, 0, 0);
}

// ---------------- fp32 -> f16 cast ------------------------------------------
__global__ __launch_bounds__(256) void k_cvt(
    const float* __restrict__ s, f16* __restrict__ d, int n)
{
    int i = blockIdx.x * 256 + threadIdx.x;
    if (i < n) d[i] = (f16)s[i];
}

// ---------------- downsample: 4x4/4 conv, 3->256 ch, NCHW -> (row, c) f16 ---
__global__ __launch_bounds__(256) void k_downsample(
    const float* __restrict__ limg, const float* __restrict__ rimg,
    const float* __restrict__ w, const float* __restrict__ bias,
    f16* __restrict__ F)
{
    __shared__ float wS[12288];   // [c][48]
    __shared__ float pS[768];     // [pix][48]
    int t = threadIdx.x;
    int bid = blockIdx.x;               // og(8) | oy(64) | b(4) | side(2)
    int og = bid & 7;
    int oy = (bid >> 3) & 63;
    int b  = (bid >> 9) & 3;
    int side = bid >> 11;
    const float* img = side ? rimg : limg;

    for (int e = t * 4; e < 12288; e += 1024)
        *(float4*)(wS + e) = *(const float4*)(w + e);

    int ox0 = og * 16;
    for (int f = t; f < 768; f += 256) {
        int kx = f & 3, pix = (f >> 2) & 15, ky = (f >> 6) & 3, ci = f >> 8;
        float v = img[((b * 3 + ci) * 256 + oy * 4 + ky) * 512 + ox0 * 4 + pix * 4 + kx];
        pS[pix * 48 + ci * 16 + ky * 4 + kx] = v;
    }
    __syncthreads();

    int c = t;
    float wreg[48];
#pragma unroll
    for (int q = 0; q < 12; q++) {
        float4 v = *(const float4*)(wS + c * 48 + q * 4);
        wreg[q * 4 + 0] = v.x; wreg[q * 4 + 1] = v.y;
        wreg[q * 4 + 2] = v.z; wreg[q * 4 + 3] = v.w;
    }
    float bv = bias[c];
    long base = ((long)(side * 32768 + b * 8192 + oy * 128 + ox0)) * 256 + c;
    for (int pix = 0; pix < 16; pix++) {
        float acc = bv;
#pragma unroll
        for (int q = 0; q < 12; q++) {
            float4 p4 = *(const float4*)(pS + pix * 48 + q * 4);
            acc += wreg[q * 4 + 0] * p4.x + wreg[q * 4 + 1] * p4.y
                 + wreg[q * 4 + 2] * p4.z + wreg[q * 4 + 3] * p4.w;
        }
        F[base + (long)pix * 256] = (f16)acc;
    }
}

// ---------------- f16 MFMA NT GEMM: C[m,n] = sum_k A[m,k]*B[n,k] ------------
// 128x128 tile, BK=64, 4 waves (2x2), each wave 4x4 frags of 16x16x32.
// M=65536 fixed (grid.x=512); rows >= 32768 go to CR. K in {256,512}.
template<typename TO>
__global__ __launch_bounds__(256) void k_gemm_mfma(
    const f16* __restrict__ A, const f16* __restrict__ B,
    TO* __restrict__ CL, TO* __restrict__ CR, int K, int ldc)
{
    __shared__ f16 As[128 * 64];
    __shared__ f16 Bs[128 * 64];
    int t = threadIdx.x;
    int w = t >> 6, lane = t & 63;
    int wm = w >> 1, wn = w & 1;
    long m0 = (long)blockIdx.x * 128;
    int n0 = blockIdx.y * 128;

    f32x4 acc[4][4] = {};

    const f16* ga = A + (m0 + w * 8 + (lane >> 3)) * K + (lane & 7) * 8;
    const f16* gb = B + ((long)n0 + w * 8 + (lane >> 3)) * K + (lane & 7) * 8;
    f16* la = As + (w * 8) * 64;     // + lane*16B implicit
    f16* lb = Bs + (w * 8) * 64;

    for (int kk = 0; kk < K; kk += 64) {
#pragma unroll
        for (int i = 0; i < 4; i++) {
            gload_lds16(ga + (long)i * 32 * K + kk, la + i * 32 * 64);
            gload_lds16(gb + (long)i * 32 * K + kk, lb + i * 32 * 64);
        }
        __syncthreads();

        const f16* pa = As + (wm * 64 + (lane & 15)) * 64 + (lane >> 4) * 8;
        const f16* pb = Bs + (wn * 64 + (lane & 15)) * 64 + (lane >> 4) * 8;
#pragma unroll
        for (int kb = 0; kb < 2; kb++) {
            f16x8 af[4], bf[4];
#pragma unroll
            for (int r = 0; r < 4; r++)
                af[r] = *(const f16x8*)(pa + r * 16 * 64 + kb * 32);
#pragma unroll
            for (int cn = 0; cn < 4; cn++)
                bf[cn] = *(const f16x8*)(pb + cn * 16 * 64 + kb * 32);
#pragma unroll
            for (int r = 0; r < 4; r++)
#pragma unroll
                for (int cn = 0; cn < 4; cn++)
                    acc[r][cn] = __builtin_amdgcn_mfma_f32_16x16x32_f16(
                        af[r], bf[cn], acc[r][cn], 0, 0, 0);
        }
        __syncthreads();
    }

    int rb = (lane >> 4) * 4;
    int cb = lane & 15;
#pragma unroll
    for (int r = 0; r < 4; r++) {
        long mrow = m0 + wm * 64 + r * 16 + rb;
#pragma unroll
        for (int reg = 0; reg < 4; reg++) {
            long row = mrow + reg;
            TO* Cp = (row < 32768) ? CL + row * ldc : CR + (row - 32768) * ldc;
#pragma unroll
            for (int cn = 0; cn < 4; cn++)
                Cp[n0 + wn * 64 + cn * 16 + cb] = (TO)acc[r][cn][reg];
        }
    }
}

// ---------------- dt: fp32 dot of F16 row with W rows 1152..1155, softplus --
__global__ __launch_bounds__(256) void k_dt(
    const f16* __restrict__ F, const float* __restrict__ W,
    const float* __restrict__ dt_bias, float* __restrict__ dtbuf)
{
    int t = threadIdx.x;
    int wv = t >> 6, lane = t & 63;
    long m = (long)blockIdx.x * 4 + wv;     // 0..65535
    f16x4 fv = *(const f16x4*)(F + m * 256 + lane * 4);
    float dots[4];
#pragma unroll
    for (int h = 0; h < 4; h++) {
        float4 w4 = *(const float4*)(W + (long)(1152 + h) * 256 + lane * 4);
        float d = (float)fv[0] * w4.x + (float)fv[1] * w4.y
                + (float)fv[2] * w4.z + (float)fv[3] * w4.w;
#pragma unroll
        for (int off = 32; off; off >>= 1) d += __shfl_down(d, off, 64);
        dots[h] = d;
    }
    if (lane == 0) {
        long sb = m >> 13;                  // side*4 + b
        long l = m & 8191;
#pragma unroll
        for (int h = 0; h < 4; h++) {
            float v = dots[h] + dt_bias[h];
            float sp = (v > 20.0f) ? v : log1pf(expf(v));
            dtbuf[(sb * 4 + h) * 8192 + l] = sp;
        }
    }
}

// ---------------- per-chunk cumsum of dt*A and per-step decay exp(dt*A) -----
__global__ __launch_bounds__(256) void k_cum(
    const float* __restrict__ dtbuf, const float* __restrict__ A_log,
    float* __restrict__ cumbuf, float* __restrict__ esbuf)
{
    int g = blockIdx.x * 256 + threadIdx.x;     // 2048 = sb(8)*h(4)*c(64)
    if (g >= 2048) return;
    int c = g & 63, h = (g >> 6) & 3, sb = g >> 8;
    float A = -expf(A_log[h]);
    long base = ((long)sb * 4 + h) * 8192 + c * 128;
    float run = 0.f;
    for (int i = 0; i < 128; i++) {
        float a = dtbuf[base + i] * A;
        run += a;
        cumbuf[base + i] = run;
        esbuf[base + i] = expf(a);
    }
}

// ---------------- causal depthwise conv1d (k=4) + bias + silu, left only ----
__global__ __launch_bounds__(256) void k_conv1d(
    const __half* __restrict__ xbcL, const float* __restrict__ cw,
    const float* __restrict__ cb, __half* __restrict__ XC)
{
    long idx = (long)blockIdx.x * 256 + threadIdx.x;    // 32768*640
    if (idx >= (long)32768 * 640) return;
    int cc = (int)(idx % 640);
    long row = idx / 640;
    int l = (int)(row & 8191);
    float acc = cb[cc];
#pragma unroll
    for (int k = 0; k < 4; k++) {
        int j = l - 3 + k;
        if (j >= 0) acc += cw[cc * 4 + k] * __half2float(xbcL[(row - 3 + k) * 640 + cc]);
    }
    XC[row * 640 + cc] = __float2half(siluf(acc));
}

// ---------------- SSD phase A: per-(side,b,chunk,head) recurrence -----------
// LDS: Bs (dt-folded) [128][64] fp32 + Cs [128][64] fp32 = 65536 B exactly.
__global__ __launch_bounds__(256) void k_ssd_a(
    const __half* __restrict__ xbcR, const __half* __restrict__ XC,
    const float* __restrict__ dtbuf, const float* __restrict__ esbuf,
    const float* __restrict__ Dvec, __half* __restrict__ ybuf,
    __half* __restrict__ states)
{
    extern __shared__ float sm[];
    float* Bs = sm;            // [i=128][n=64], pre-multiplied by dt_i
    float* Cs = sm + 8192;     // [i=128][n=64]

    int t = threadIdx.x;
    int bid = blockIdx.x;
    int side = bid >> 10;
    int rem = bid & 1023;
    int b = rem >> 8, c = (rem >> 2) & 63, h = rem & 3;
    long l0 = (long)b * 8192 + c * 128;

    const __half *xsrc, *Bsrc, *Csrc;
    if (side == 0) { xsrc = xbcR; Bsrc = xbcR + 512; Csrc = XC + 576; }
    else           { xsrc = XC;   Bsrc = XC + 512;   Csrc = xbcR + 576; }

    long dtbase = ((long)(side * 4 + b) * 4 + h) * 8192 + c * 128;

    for (int e = t * 4; e < 8192; e += 1024) {
        int i = e >> 6, n = e & 63;
        float dti = dtbuf[dtbase + i];
        const __half2* bp = (const __half2*)(Bsrc + (l0 + i) * 640 + n);
        float2 b0 = __half22float2(bp[0]), b1 = __half22float2(bp[1]);
        Bs[e + 0] = dti * b0.x; Bs[e + 1] = dti * b0.y;
        Bs[e + 2] = dti * b1.x; Bs[e + 3] = dti * b1.y;
        const __half2* cp = (const __half2*)(Csrc + (l0 + i) * 640 + n);
        float2 c0 = __half22float2(cp[0]), c1 = __half22float2(cp[1]);
        Cs[e + 0] = c0.x; Cs[e + 1] = c0.y; Cs[e + 2] = c1.x; Cs[e + 3] = c1.y;
    }
    __syncthreads();

    int nh = t & 1;
    int p = t >> 1;
    float hreg[32];
#pragma unroll
    for (int q = 0; q < 32; q++) hreg[q] = 0.f;
    float Dh = Dvec[h];
    const __half* xcol = xsrc + l0 * 640 + h * 128 + p;
    long ybase = ((long)side * 32768 + l0) * 512 + h * 128 + p;

    for (int i = 0; i < 128; i++) {
        float dec = esbuf[dtbase + i];
        float xv = __half2float(xcol[(long)i * 640]);
        const float* brow = Bs + i * 64 + nh * 32;
        const float* crow = Cs + i * 64 + nh * 32;
        float accp = 0.f;
#pragma unroll
        for (int q = 0; q < 8; q++) {
            float4 b4 = *(const float4*)(brow + q * 4);
            float4 c4 = *(const float4*)(crow + q * 4);
            hreg[q * 4 + 0] = dec * hreg[q * 4 + 0] + b4.x * xv;
            hreg[q * 4 + 1] = dec * hreg[q * 4 + 1] + b4.y * xv;
            hreg[q * 4 + 2] = dec * hreg[q * 4 + 2] + b4.z * xv;
            hreg[q * 4 + 3] = dec * hreg[q * 4 + 3] + b4.w * xv;
            accp += c4.x * hreg[q * 4 + 0] + c4.y * hreg[q * 4 + 1]
                  + c4.z * hreg[q * 4 + 2] + c4.w * hreg[q * 4 + 3];
        }
        accp += __shfl_xor(accp, 1, 64);
        if (nh == 0) ybuf[ybase + (long)i * 512] = __float2half(accp + Dh * xv);
    }
    // states[(side*4+b)][c][h][p][n] fp16
    long sbase = ((((long)(side * 4 + b) * 64 + c) * 4 + h) * 128 + p) * 64 + nh * 32;
    __half2* sp = (__half2*)(states + sbase);
#pragma unroll
    for (int q = 0; q < 16; q++)
        sp[q] = __floats2half2_rn(hreg[2 * q], hreg[2 * q + 1]);
}

// ---------------- inter-chunk scan over 64 chunks (in place, fp16) ----------
__global__ __launch_bounds__(256) void k_scan(
    __half* __restrict__ states, const float* __restrict__ cumbuf)
{
    long g = (long)blockIdx.x * 256 + threadIdx.x;   // 262144 threads
    int n = (int)(g & 63);
    int p = (int)((g >> 6) & 127);
    int h = (int)((g >> 13) & 3);
    int sb = (int)(g >> 15);                         // side*4+b
    long sbase = (((long)sb * 256 + h) * 128 + p) * 64 + n;   // c=0
    long cbase = ((long)sb * 4 + h) * 8192 + 127;
    float hr = 0.f;
    for (int c = 0; c < 64; c++) {
        long idx = sbase + (long)c * 32768;
        float dec = expf(cumbuf[cbase + (long)c * 128]);
        float s = __half2float(states[idx]);
        states[idx] = __float2half(hr);          // hprev for chunk c
        hr = hr * dec + s;
    }
}

// ---------------- SSD phase C: y += exp(cum_i) * C_i . hprev ----------------
// LDS: Ct fp16 [64][136] + Ht fp16 [64][136] = 34816 B.
__global__ __launch_bounds__(256) void k_ssd_c(
    const __half* __restrict__ xbcR, const __half* __restrict__ XC,
    const __half* __restrict__ states, const float* __restrict__ cumbuf,
    __half* __restrict__ ybuf)
{
    extern __shared__ __half smh[];
    __half* Ct = smh;                // [n=64][i=128] pad 136
    __half* Ht = smh + 64 * 136;     // [n=64][p=128] pad 136
    int tx = threadIdx.x, ty = threadIdx.y;
    int t = ty * 16 + tx;
    int bid = blockIdx.x;
    int side = bid >> 10;
    int rem = bid & 1023;
    int b = rem >> 8, c = (rem >> 2) & 63, h = rem & 3;
    long l0 = (long)b * 8192 + c * 128;

    const __half* Csrc = (side == 0) ? XC + 576 : xbcR + 576;

    for (int e = t * 4; e < 8192; e += 1024) {
        int i = e >> 6, n = e & 63;
        const __half2* cp = (const __half2*)(Csrc + (l0 + i) * 640 + n);
        __half2 c0 = cp[0], c1 = cp[1];
        Ct[(n + 0) * 136 + i] = __low2half(c0);
        Ct[(n + 1) * 136 + i] = __high2half(c0);
        Ct[(n + 2) * 136 + i] = __low2half(c1);
        Ct[(n + 3) * 136 + i] = __high2half(c1);
    }
    long sb2 = (long)side * 4 + b;
    long stile = ((sb2 * 64 + c) * 4 + h) * 8192;
    for (int e = t * 4; e < 8192; e += 1024) {
        int p = e >> 6, n = e & 63;
        const __half2* spt = (const __half2*)(states + stile + e);
        __half2 s0 = spt[0], s1 = spt[1];
        Ht[(n + 0) * 136 + p] = __low2half(s0);
        Ht[(n + 1) * 136 + p] = __high2half(s0);
        Ht[(n + 2) * 136 + p] = __low2half(s1);
        Ht[(n + 3) * 136 + p] = __high2half(s1);
    }
    __syncthreads();

    float acc[8][8] = {};
#pragma unroll 4
    for (int k = 0; k < 64; k++) {
        const __half2* cr = (const __half2*)(Ct + k * 136 + ty * 8);
        const __half2* hr = (const __half2*)(Ht + k * 136 + tx * 8);
        float av[8], bv[8];
#pragma unroll
        for (int j = 0; j < 4; j++) {
            float2 u = __half22float2(cr[j]);
            av[2 * j] = u.x; av[2 * j + 1] = u.y;
            float2 w = __half22float2(hr[j]);
            bv[2 * j] = w.x; bv[2 * j + 1] = w.y;
        }
#pragma unroll
        for (int i = 0; i < 8; i++)
#pragma unroll
            for (int j = 0; j < 8; j++)
                acc[i][j] += av[i] * bv[j];
    }
    long dtbase = (sb2 * 4 + h) * 8192 + c * 128;
    long ybase = ((long)side * 32768 + l0) * 512 + h * 128;
#pragma unroll
    for (int i = 0; i < 8; i++) {
        int ii = ty * 8 + i;
        float ex = expf(cumbuf[dtbase + ii]);
        __half2* yrow = (__half2*)(ybuf + ybase + (long)ii * 512 + tx * 8);
#pragma unroll
        for (int j = 0; j < 4; j++) {
            float2 o = __half22float2(yrow[j]);
            o.x += ex * acc[i][2 * j];
            o.y += ex * acc[i][2 * j + 1];
            yrow[j] = __floats2half2_rn(o.x, o.y);
        }
    }
}

// ---------------- gated rmsnorm: y = rmsnorm(y * silu(z)) * w  (in place) ---
__global__ __launch_bounds__(256) void k_rmsnorm(
    __half* __restrict__ ybuf, const __half* __restrict__ zbuf,
    const float* __restrict__ nw)
{
    int t = threadIdx.x;
    int wv = t >> 6, lane = t & 63;
    long r = (long)blockIdx.x * 4 + wv;
    __half2* yrow = (__half2*)(ybuf + r * 512 + lane * 8);
    const __half2* zrow = (const __half2*)(zbuf + r * 512 + lane * 8);
    float g[8];
#pragma unroll
    for (int j = 0; j < 4; j++) {
        float2 yv = __half22float2(yrow[j]);
        float2 zv = __half22float2(zrow[j]);
        g[2 * j]     = yv.x * siluf(zv.x);
        g[2 * j + 1] = yv.y * siluf(zv.y);
    }
    float ss = 0.f;
#pragma unroll
    for (int i = 0; i < 8; i++) ss += g[i] * g[i];
#pragma unroll
    for (int off = 32; off; off >>= 1) ss += __shfl_xor(ss, off, 64);
    float sc = rsqrtf(ss * (1.0f / 512.0f) + 1e-5f);
#pragma unroll
    for (int j = 0; j < 4; j++) {
        float w0 = nw[lane * 8 + 2 * j], w1 = nw[lane * 8 + 2 * j + 1];
        yrow[j] = __floats2half2_rn(g[2 * j] * sc * w0, g[2 * j + 1] * sc * w1);
    }
}

// ---------------------------------------------------------------------------
extern "C" void kernel_launch(void* const* d_in, const int* in_sizes, int n_in,
                              void* d_out, int out_size, void* d_ws, size_t ws_size,
                              hipStream_t stream)
{
    (void)in_sizes; (void)n_in; (void)out_size; (void)ws_size;
    const float* limg = (const float*)d_in[0];
    const float* rimg = (const float*)d_in[1];
    const float* dsw  = (const float*)d_in[2];
    const float* dsb  = (const float*)d_in[3];
    const float* ipw  = (const float*)d_in[4];
    const float* cw   = (const float*)d_in[5];
    const float* cb   = (const float*)d_in[6];
    const float* dtb  = (const float*)d_in[7];
    const float* alog = (const float*)d_in[8];
    const float* Dv   = (const float*)d_in[9];
    const float* nw   = (const float*)d_in[10];
    const float* opw  = (const float*)d_in[11];
    float* out = (float*)d_out;

    char* ws = (char*)d_ws;
    f16*    F16    = (f16*)   (ws + 0);
    f16*    ipw16  = (f16*)   (ws + 33554432);
    f16*    opw16  = (f16*)   (ws + 34146304);
    float*  dtbuf  = (float*) (ws + 34408448);
    float*  esbuf  = (float*) (ws + 35457024);
    float*  cumbuf = (float*) (ws + 36505600);
    __half* xbcR   = (__half*)(ws + 37554176);
    __half* XC     = (__half*)(ws + 79497216);
    __half* ybuf   = (__half*)(ws + 121440256);
    __half* xbcL   = ybuf;                        // alias, dead before ssd_a
    __half* states = (__half*)(ws + 188549120);
    __half* zbuf   = (__half*)(ws + 37554176);    // alias over dead xbcR+XC

    k_downsample<<<4096, 256, 0, stream>>>(limg, rimg, dsw, dsb, F16);
    k_cvt<<<1156, 256, 0, stream>>>(ipw, ipw16, 1156 * 256);
    k_cvt<<<512, 256, 0, stream>>>(opw, opw16, 256 * 512);
    // in_proj, xBC columns (ipw rows 512..1151)
    k_gemm_mfma<f16><<<dim3(512, 5), 256, 0, stream>>>(
        F16, ipw16 + 512 * 256, (f16*)xbcL, (f16*)xbcR, 256, 640);
    k_dt<<<16384, 256, 0, stream>>>(F16, ipw, dtb, dtbuf);
    k_cum<<<8, 256, 0, stream>>>(dtbuf, alog, cumbuf, esbuf);
    k_conv1d<<<81920, 256, 0, stream>>>(xbcL, cw, cb, XC);
    k_ssd_a<<<2048, 256, 65536, stream>>>(xbcR, XC, dtbuf, esbuf, Dv, ybuf, states);
    k_scan<<<1024, 256, 0, stream>>>(states, cumbuf);
    k_ssd_c<<<2048, dim3(16, 16), 34816, stream>>>(xbcR, XC, states, cumbuf, ybuf);
    // z = F @ ipw[0:512]^T  (into region freed by xbcR/XC)
    k_gemm_mfma<f16><<<dim3(512, 4), 256, 0, stream>>>(
        F16, ipw16, (f16*)zbuf, (f16*)(zbuf + (long)32768 * 512), 256, 512);
    k_rmsnorm<<<16384, 256, 0, stream>>>(ybuf, zbuf, nw);
    // out = y @ opw^T (fp32 out)
    k_gemm_mfma<float><<<dim3(512, 2), 256, 0, stream>>>(
        (const f16*)ybuf, opw16, out, out + (long)32768 * 256, 512, 256);
}

// Round 4
// 568.386 us; speedup vs baseline: 2.7929x; 1.4934x over previous
//
#include <hip/hip_runtime.h>
#include <hip/hip_fp16.h>
#include <math.h>

// ---------------------------------------------------------------------------
// Mamba2 stereo SSD block. All GEMM-shaped work on f16 MFMA; fp32 dt/cum/exp.
// B=4, L=8192 (64x128), D_MODEL=256, D_INNER=512, NHEADS=4, HEADDIM=128,
// D_STATE=64, CONV_DIM=640, CHUNK=128, NCHUNK=64.
//
// SSD per-tile formulation (side,b,chunk,head):
//   G = C (128x64) . B^T (64x128)            [MFMA, K=64]
//   M_ij = (i>=j) ? G_ij*exp(cum_i-cum_j)*dt_j : 0 ;  M_ii += D_h
//   Y = M (128x128) . X (128lx128p)          [MFMA, K=128]  (D*x folded in M)
//   states_pn = sum_j X_jp * B_jn * dt_j*exp(cumL-cum_j)   [MFMA, K=128]
// then inter-chunk scan; correction Y += exp(cum_i) * C . hprev^T [MFMA].
// X is produced TRANSPOSED ([channel][Lglobal]) by the in_proj GEMM so MFMA
// operands are K-contiguous; causal conv on x runs along contiguous L.
//
// Workspace (bytes), total 264,046,592 (~252 MiB):
//   F16    f16 [65536,256]    [0,          33,554,432)
//   ipw16  f16 [1156,256]     [33,554,432, 34,146,304)
//   opw16  f16 [256,512]      [34,146,304, 34,408,448)
//   dtbuf  f32 [8,4,8192]     [34,408,448, 35,457,024)
//   cumbuf f32 [8,4,8192]     [35,457,024, 36,505,600)
//   wbuf   f32 [8,4,8192]     [36,505,600, 37,554,176)
//   xT     f16 [512,65536]    [37,554,176, 104,663,040)  live: gemm -> ssd_a
//   XCt    f16 [512,32768]    [104,663,040,138,217,472)  live: conv -> ssd_a
//   bcLr   f16 [32768,128]    [138,217,472,146,606,080)  raw left B/C
//   bcR    f16 [32768,128]    [146,606,080,154,994,688)  raw right B/C
//   bcL    f16 [32768,128]    [154,994,688,163,383,296)  conv'd left B/C
//   ybuf   f16 [65536,512]    [163,383,296,230,492,160)
//   states f16 [8,64,4,128,64][230,492,160,264,046,592)
//   zbuf   f16 [65536,512]    alias over dead xT
// ---------------------------------------------------------------------------

typedef _Float16 f16;
typedef __attribute__((ext_vector_type(8))) _Float16 f16x8;
typedef __attribute__((ext_vector_type(4))) _Float16 f16x4;
typedef __attribute__((ext_vector_type(4))) float f32x4;

__device__ __forceinline__ float siluf(float v) { return v / (1.0f + expf(-v)); }

__device__ __forceinline__ void gload_lds16(const void* g, void* l) {
    __builtin_amdgcn_global_load_lds(
        (const __attribute__((address_space(1))) void*)g,
        (__attribute__((address_space(3))) void*)l, 16, 0, 0);
}

// ---------------- fp32 -> f16 cast ------------------------------------------
__global__ __launch_bounds__(256) void k_cvt(
    const float* __restrict__ s, f16* __restrict__ d, int n)
{
    int i = blockIdx.x * 256 + threadIdx.x;
    if (i < n) d[i] = (f16)s[i];
}

// ---------------- downsample: 4x4/4 conv, 3->256 ch, NCHW -> (row, c) f16 ---
__global__ __launch_bounds__(256) void k_downsample(
    const float* __restrict__ limg, const float* __restrict__ rimg,
    const float* __restrict__ w, const float* __restrict__ bias,
    f16* __restrict__ F)
{
    __shared__ float wS[12288];   // [c][48]
    __shared__ float pS[768];     // [pix][48]
    int t = threadIdx.x;
    int bid = blockIdx.x;               // og(8) | oy(64) | b(4) | side(2)
    int og = bid & 7;
    int oy = (bid >> 3) & 63;
    int b  = (bid >> 9) & 3;
    int side = bid >> 11;
    const float* img = side ? rimg : limg;

    for (int e = t * 4; e < 12288; e += 1024)
        *(float4*)(wS + e) = *(const float4*)(w + e);

    int ox0 = og * 16;
    for (int f = t; f < 768; f += 256) {
        int kx = f & 3, pix = (f >> 2) & 15, ky = (f >> 6) & 3, ci = f >> 8;
        float v = img[((b * 3 + ci) * 256 + oy * 4 + ky) * 512 + ox0 * 4 + pix * 4 + kx];
        pS[pix * 48 + ci * 16 + ky * 4 + kx] = v;
    }
    __syncthreads();

    int c = t;
    float wreg[48];
#pragma unroll
    for (int q = 0; q < 12; q++) {
        float4 v = *(const float4*)(wS + c * 48 + q * 4);
        wreg[q * 4 + 0] = v.x; wreg[q * 4 + 1] = v.y;
        wreg[q * 4 + 2] = v.z; wreg[q * 4 + 3] = v.w;
    }
    float bv = bias[c];
    long base = ((long)(side * 32768 + b * 8192 + oy * 128 + ox0)) * 256 + c;
    for (int pix = 0; pix < 16; pix++) {
        float acc = bv;
#pragma unroll
        for (int q = 0; q < 12; q++) {
            float4 p4 = *(const float4*)(pS + pix * 48 + q * 4);
            acc += wreg[q * 4 + 0] * p4.x + wreg[q * 4 + 1] * p4.y
                 + wreg[q * 4 + 2] * p4.z + wreg[q * 4 + 3] * p4.w;
        }
        F[base + (long)pix * 256] = (f16)acc;
    }
}

// ---------------- f16 MFMA NT GEMM: C[m,n] = sum_k A[m,k]*B[n,k] ------------
// 128x128 tile, BK=64, 4 waves (2x2), each wave 4x4 frags of 16x16x32.
// lda = ldb = K. Output rows >= split go to CR (row-split).
template<typename TO>
__global__ __launch_bounds__(256) void k_gemm_mfma(
    const f16* __restrict__ A, const f16* __restrict__ B,
    TO* __restrict__ CL, TO* __restrict__ CR, int K, int ldc, int split)
{
    __shared__ f16 As[128 * 64];
    __shared__ f16 Bs[128 * 64];
    int t = threadIdx.x;
    int w = t >> 6, lane = t & 63;
    int wm = w >> 1, wn = w & 1;
    long m0 = (long)blockIdx.x * 128;
    int n0 = blockIdx.y * 128;

    f32x4 acc[4][4] = {};

    const f16* ga = A + (m0 + w * 8 + (lane >> 3)) * K + (lane & 7) * 8;
    const f16* gb = B + ((long)n0 + w * 8 + (lane >> 3)) * K + (lane & 7) * 8;
    f16* la = As + (w * 8) * 64;
    f16* lb = Bs + (w * 8) * 64;

    for (int kk = 0; kk < K; kk += 64) {
#pragma unroll
        for (int i = 0; i < 4; i++) {
            gload_lds16(ga + (long)i * 32 * K + kk, la + i * 32 * 64);
            gload_lds16(gb + (long)i * 32 * K + kk, lb + i * 32 * 64);
        }
        __syncthreads();

        const f16* pa = As + (wm * 64 + (lane & 15)) * 64 + (lane >> 4) * 8;
        const f16* pb = Bs + (wn * 64 + (lane & 15)) * 64 + (lane >> 4) * 8;
#pragma unroll
        for (int kb = 0; kb < 2; kb++) {
            f16x8 af[4], bf[4];
#pragma unroll
            for (int r = 0; r < 4; r++)
                af[r] = *(const f16x8*)(pa + r * 16 * 64 + kb * 32);
#pragma unroll
            for (int cn = 0; cn < 4; cn++)
                bf[cn] = *(const f16x8*)(pb + cn * 16 * 64 + kb * 32);
#pragma unroll
            for (int r = 0; r < 4; r++)
#pragma unroll
                for (int cn = 0; cn < 4; cn++)
                    acc[r][cn] = __builtin_amdgcn_mfma_f32_16x16x32_f16(
                        af[r], bf[cn], acc[r][cn], 0, 0, 0);
        }
        __syncthreads();
    }

    int rb = (lane >> 4) * 4;
    int cb = lane & 15;
#pragma unroll
    for (int r = 0; r < 4; r++) {
        long mrow = m0 + wm * 64 + r * 16 + rb;
#pragma unroll
        for (int reg = 0; reg < 4; reg++) {
            long row = mrow + reg;
            TO* Cp = (row < split) ? CL + row * ldc : CR + (row - split) * ldc;
#pragma unroll
            for (int cn = 0; cn < 4; cn++)
                Cp[n0 + wn * 64 + cn * 16 + cb] = (TO)acc[r][cn][reg];
        }
    }
}

// ---------------- dt: fp32 dot of F16 row with W rows 1152..1155, softplus --
__global__ __launch_bounds__(256) void k_dt(
    const f16* __restrict__ F, const float* __restrict__ W,
    const float* __restrict__ dt_bias, float* __restrict__ dtbuf)
{
    int t = threadIdx.x;
    int wv = t >> 6, lane = t & 63;
    long m = (long)blockIdx.x * 4 + wv;     // 0..65535
    f16x4 fv = *(const f16x4*)(F + m * 256 + lane * 4);
    float dots[4];
#pragma unroll
    for (int h = 0; h < 4; h++) {
        float4 w4 = *(const float4*)(W + (long)(1152 + h) * 256 + lane * 4);
        float d = (float)fv[0] * w4.x + (float)fv[1] * w4.y
                + (float)fv[2] * w4.z + (float)fv[3] * w4.w;
#pragma unroll
        for (int off = 32; off; off >>= 1) d += __shfl_down(d, off, 64);
        dots[h] = d;
    }
    if (lane == 0) {
        long sb = m >> 13;                  // side*4 + b
        long l = m & 8191;
#pragma unroll
        for (int h = 0; h < 4; h++) {
            float v = dots[h] + dt_bias[h];
            float sp = (v > 20.0f) ? v : log1pf(expf(v));
            dtbuf[(sb * 4 + h) * 8192 + l] = sp;
        }
    }
}

// ---------------- per-chunk cumsum of dt*A, and w = dt*exp(cumL-cum) --------
__global__ __launch_bounds__(256) void k_cum(
    const float* __restrict__ dtbuf, const float* __restrict__ A_log,
    float* __restrict__ cumbuf, float* __restrict__ wbuf)
{
    int g = blockIdx.x * 256 + threadIdx.x;     // 2048 = sb(8)*h(4)*c(64)
    if (g >= 2048) return;
    int c = g & 63, h = (g >> 6) & 3, sb = g >> 8;
    float A = -expf(A_log[h]);
    long base = ((long)sb * 4 + h) * 8192 + c * 128;
    float run = 0.f;
    for (int i = 0; i < 128; i++) {
        run += dtbuf[base + i] * A;
        cumbuf[base + i] = run;
    }
    float cl = run;
    for (int i = 0; i < 128; i++)
        wbuf[base + i] = dtbuf[base + i] * expf(cl - cumbuf[base + i]);
}

// ---------------- causal conv1d on transposed x (contiguous along L) --------
__global__ __launch_bounds__(256) void k_conv_x(
    const f16* __restrict__ xT, const float* __restrict__ cw,
    const float* __restrict__ cb, f16* __restrict__ XCt)
{
    int bid = blockIdx.x;               // c(512) | b(4) | tile(4)
    int c = bid >> 4;
    int b = (bid >> 2) & 3;
    int tile = bid & 3;
    int l0 = tile * 2048 + threadIdx.x * 8;
    const f16* row = xT + (long)c * 65536 + b * 8192;   // left cols only
    float w0 = cw[c * 4 + 0], w1 = cw[c * 4 + 1],
          w2 = cw[c * 4 + 2], w3 = cw[c * 4 + 3];
    float bv = cb[c];
    float xv[11];
    f16x8 v = *(const f16x8*)(row + l0);
#pragma unroll
    for (int q = 0; q < 8; q++) xv[3 + q] = (float)v[q];
    if (l0 > 0) {
        xv[0] = (float)row[l0 - 3];
        xv[1] = (float)row[l0 - 2];
        xv[2] = (float)row[l0 - 1];
    } else { xv[0] = xv[1] = xv[2] = 0.f; }
    f16x8 o;
#pragma unroll
    for (int q = 0; q < 8; q++) {
        float acc = bv + w0 * xv[q] + w1 * xv[q + 1] + w2 * xv[q + 2] + w3 * xv[q + 3];
        o[q] = (f16)siluf(acc);
    }
    *(f16x8*)(XCt + (long)c * 32768 + b * 8192 + l0) = o;
}

// ---------------- causal conv1d on left B/C (row-major [l][128]) ------------
__global__ __launch_bounds__(256) void k_conv_bc(
    const f16* __restrict__ bcLr, const float* __restrict__ cw,
    const float* __restrict__ cb, f16* __restrict__ bcL)
{
    long idx = (long)blockIdx.x * 256 + threadIdx.x;    // 32768*128
    int n = (int)(idx & 127);
    long m = idx >> 7;
    int l = (int)(m & 8191);
    float acc = cb[512 + n];
#pragma unroll
    for (int k = 0; k < 4; k++) {
        int j = l - 3 + k;
        if (j >= 0) acc += cw[(512 + n) * 4 + k] * (float)bcLr[(m - 3 + k) * 128 + n];
    }
    bcL[m * 128 + n] = (f16)siluf(acc);
}

// ---------------- SSD phase A: MFMA chunked formulation ---------------------
// LDS 64 KB: Xs[p=128][j=128] (32KB) | Cs[i=128][n=64] (16KB) | Bs[j=128][n=64]
// (16KB); Ms[i=128][j=128] overlays Cs+Bs after G.
__global__ __launch_bounds__(256) void k_ssd_a(
    const f16* __restrict__ xT, const f16* __restrict__ XCt,
    const f16* __restrict__ bcR, const f16* __restrict__ bcL,
    const float* __restrict__ dtbuf, const float* __restrict__ cumbuf,
    const float* __restrict__ wbuf, const float* __restrict__ Dvec,
    f16* __restrict__ ybuf, f16* __restrict__ states)
{
    extern __shared__ f16 sm[];
    f16* Xs = sm;            // [p][j]
    f16* Cs = sm + 16384;    // [i][n]
    f16* Bs = sm + 24576;    // [j][n]
    f16* Ms = sm + 16384;    // [i][j] overlay

    int t = threadIdx.x;
    int w = t >> 6, lane = t & 63;
    int quad = lane >> 4, l16 = lane & 15;
    int wm = w >> 1, wn = w & 1;
    int bid = blockIdx.x;
    int side = bid >> 10, rem = bid & 1023;
    int b = rem >> 8, c = (rem >> 2) & 63, h = rem & 3;
    long l0 = (long)b * 8192 + c * 128;
    long dtbase = ((long)(side * 4 + b) * 4 + h) * 8192 + c * 128;

    const f16* Xg; long ldx;
    const f16 *Bg, *Cg;
    if (side == 0) {
        Xg = xT + (long)(h * 128) * 65536 + 32768 + l0; ldx = 65536;
        Bg = bcR + l0 * 128;
        Cg = bcL + l0 * 128 + 64;
    } else {
        Xg = XCt + (long)(h * 128) * 32768 + l0;        ldx = 32768;
        Bg = bcL + l0 * 128;
        Cg = bcR + l0 * 128 + 64;
    }

    // stage X (4 rows/call), C and B (8 rows/call)
#pragma unroll
    for (int q = 0; q < 8; q++) {
        int r0 = w * 32 + q * 4;
        gload_lds16(Xg + (long)(r0 + quad) * ldx + l16 * 8, Xs + r0 * 128);
    }
#pragma unroll
    for (int q = 0; q < 4; q++) {
        int r0 = w * 32 + q * 8;
        gload_lds16(Cg + (long)(r0 + (lane >> 3)) * 128 + (lane & 7) * 8, Cs + r0 * 64);
        gload_lds16(Bg + (long)(r0 + (lane >> 3)) * 128 + (lane & 7) * 8, Bs + r0 * 64);
    }

    float cum_i[16], cum_j[4], dt_j[4];
#pragma unroll
    for (int r = 0; r < 4; r++)
#pragma unroll
        for (int reg = 0; reg < 4; reg++)
            cum_i[r * 4 + reg] = cumbuf[dtbase + wm * 64 + r * 16 + quad * 4 + reg];
#pragma unroll
    for (int cn = 0; cn < 4; cn++) {
        int j = wn * 64 + cn * 16 + l16;
        cum_j[cn] = cumbuf[dtbase + j];
        dt_j[cn] = dtbuf[dtbase + j];
    }
    float Dh = Dvec[h];
    __syncthreads();

    // G = C . B^T  (K=64)
    f32x4 g[4][4] = {};
#pragma unroll
    for (int kb = 0; kb < 2; kb++) {
        f16x8 af[4], bf[4];
#pragma unroll
        for (int r = 0; r < 4; r++)
            af[r] = *(const f16x8*)(Cs + (wm * 64 + r * 16 + l16) * 64 + quad * 8 + kb * 32);
#pragma unroll
        for (int cn = 0; cn < 4; cn++)
            bf[cn] = *(const f16x8*)(Bs + (wn * 64 + cn * 16 + l16) * 64 + quad * 8 + kb * 32);
#pragma unroll
        for (int r = 0; r < 4; r++)
#pragma unroll
            for (int cn = 0; cn < 4; cn++)
                g[r][cn] = __builtin_amdgcn_mfma_f32_16x16x32_f16(
                    af[r], bf[cn], g[r][cn], 0, 0, 0);
    }
    __syncthreads();

    // M = mask(G)*exp*dt (+D on diagonal), write f16 to LDS (overlay Cs/Bs)
#pragma unroll
    for (int r = 0; r < 4; r++)
#pragma unroll
        for (int cn = 0; cn < 4; cn++)
#pragma unroll
            for (int reg = 0; reg < 4; reg++) {
                int i = wm * 64 + r * 16 + quad * 4 + reg;
                int j = wn * 64 + cn * 16 + l16;
                float v = 0.f;
                if (i >= j)
                    v = g[r][cn][reg] * expf(cum_i[r * 4 + reg] - cum_j[cn]) * dt_j[cn];
                if (i == j) v += Dh;
                Ms[i * 128 + j] = (f16)v;
            }
    __syncthreads();

    // Y = M . X   (K=128): A=Ms[i][j], B=Xs[p][j]
    f32x4 y[4][4] = {};
#pragma unroll
    for (int kb = 0; kb < 4; kb++) {
        f16x8 af[4], bf[4];
#pragma unroll
        for (int r = 0; r < 4; r++)
            af[r] = *(const f16x8*)(Ms + (wm * 64 + r * 16 + l16) * 128 + quad * 8 + kb * 32);
#pragma unroll
        for (int cn = 0; cn < 4; cn++)
            bf[cn] = *(const f16x8*)(Xs + (wn * 64 + cn * 16 + l16) * 128 + quad * 8 + kb * 32);
#pragma unroll
        for (int r = 0; r < 4; r++)
#pragma unroll
            for (int cn = 0; cn < 4; cn++)
                y[r][cn] = __builtin_amdgcn_mfma_f32_16x16x32_f16(
                    af[r], bf[cn], y[r][cn], 0, 0, 0);
    }
    long ybase = (long)side * 32768 + l0;
#pragma unroll
    for (int r = 0; r < 4; r++)
#pragma unroll
        for (int reg = 0; reg < 4; reg++) {
            int i = wm * 64 + r * 16 + quad * 4 + reg;
#pragma unroll
            for (int cn = 0; cn < 4; cn++) {
                int p = wn * 64 + cn * 16 + l16;
                ybuf[(ybase + i) * 512 + h * 128 + p] = (f16)y[r][cn][reg];
            }
        }

    // states = X^T(weighted B): A=Xs[p][j], B-frags built from global B * w_j
    f32x4 s[4][2] = {};
#pragma unroll
    for (int kb = 0; kb < 4; kb++) {
        float wj[8];
#pragma unroll
        for (int jj = 0; jj < 8; jj++)
            wj[jj] = wbuf[dtbase + kb * 32 + quad * 8 + jj];
        f16x8 af[4], bf[2];
#pragma unroll
        for (int r = 0; r < 4; r++)
            af[r] = *(const f16x8*)(Xs + (wm * 64 + r * 16 + l16) * 128 + quad * 8 + kb * 32);
#pragma unroll
        for (int cn = 0; cn < 2; cn++) {
            int n = wn * 32 + cn * 16 + l16;
#pragma unroll
            for (int jj = 0; jj < 8; jj++) {
                int j = kb * 32 + quad * 8 + jj;
                bf[cn][jj] = (f16)((float)Bg[(long)j * 128 + n] * wj[jj]);
            }
        }
#pragma unroll
        for (int r = 0; r < 4; r++)
#pragma unroll
            for (int cn = 0; cn < 2; cn++)
                s[r][cn] = __builtin_amdgcn_mfma_f32_16x16x32_f16(
                    af[r], bf[cn], s[r][cn], 0, 0, 0);
    }
    long sbase = (((long)(side * 4 + b) * 64 + c) * 4 + h) * 128;
#pragma unroll
    for (int r = 0; r < 4; r++)
#pragma unroll
        for (int reg = 0; reg < 4; reg++) {
            int p = wm * 64 + r * 16 + quad * 4 + reg;
#pragma unroll
            for (int cn = 0; cn < 2; cn++) {
                int n = wn * 32 + cn * 16 + l16;
                states[(sbase + p) * 64 + n] = (f16)s[r][cn][reg];
            }
        }
}

// ---------------- inter-chunk scan over 64 chunks (in place, fp16) ----------
__global__ __launch_bounds__(256) void k_scan(
    f16* __restrict__ states, const float* __restrict__ cumbuf)
{
    long g = (long)blockIdx.x * 256 + threadIdx.x;   // 262144 threads
    int n = (int)(g & 63);
    int p = (int)((g >> 6) & 127);
    int h = (int)((g >> 13) & 3);
    int sb = (int)(g >> 15);                         // side*4+b
    long sbase = (((long)sb * 256 + h) * 128 + p) * 64 + n;   // c=0
    long cbase = ((long)sb * 4 + h) * 8192 + 127;
    float hr = 0.f;
    for (int c = 0; c < 64; c++) {
        long idx = sbase + (long)c * 32768;
        float dec = expf(cumbuf[cbase + (long)c * 128]);
        float sv = (float)states[idx];
        states[idx] = (f16)hr;          // hprev for chunk c
        hr = hr * dec + sv;
    }
}

// ---------------- SSD phase C: y += exp(cum_i) * C . hprev^T  (MFMA) --------
// A = C[i][n] (global f16x8), B = states[p][n] (global f16x8). No LDS.
__global__ __launch_bounds__(256) void k_ssd_c(
    const f16* __restrict__ bcR, const f16* __restrict__ bcL,
    const f16* __restrict__ states, const float* __restrict__ cumbuf,
    f16* __restrict__ ybuf)
{
    int t = threadIdx.x;
    int w = t >> 6, lane = t & 63;
    int quad = lane >> 4, l16 = lane & 15;
    int wm = w >> 1, wn = w & 1;
    int bid = blockIdx.x;
    int side = bid >> 10, rem = bid & 1023;
    int b = rem >> 8, c = (rem >> 2) & 63, h = rem & 3;
    long l0 = (long)b * 8192 + c * 128;
    long dtbase = ((long)(side * 4 + b) * 4 + h) * 8192 + c * 128;

    const f16* Cg = (side == 0) ? bcL + l0 * 128 + 64 : bcR + l0 * 128 + 64;
    long stile = (((long)(side * 4 + b) * 64 + c) * 4 + h) * 8192;

    f32x4 acc[4][4] = {};
#pragma unroll
    for (int kb = 0; kb < 2; kb++) {
        f16x8 af[4], bf[4];
#pragma unroll
        for (int r = 0; r < 4; r++)
            af[r] = *(const f16x8*)(Cg + (long)(wm * 64 + r * 16 + l16) * 128 + quad * 8 + kb * 32);
#pragma unroll
        for (int cn = 0; cn < 4; cn++)
            bf[cn] = *(const f16x8*)(states + stile + (long)(wn * 64 + cn * 16 + l16) * 64 + quad * 8 + kb * 32);
#pragma unroll
        for (int r = 0; r < 4; r++)
#pragma unroll
            for (int cn = 0; cn < 4; cn++)
                acc[r][cn] = __builtin_amdgcn_mfma_f32_16x16x32_f16(
                    af[r], bf[cn], acc[r][cn], 0, 0, 0);
    }
    long ybase = (long)side * 32768 + l0;
#pragma unroll
    for (int r = 0; r < 4; r++)
#pragma unroll
        for (int reg = 0; reg < 4; reg++) {
            int i = wm * 64 + r * 16 + quad * 4 + reg;
            float ex = expf(cumbuf[dtbase + i]);
            f16* yrow = ybuf + (ybase + i) * 512 + h * 128;
#pragma unroll
            for (int cn = 0; cn < 4; cn++) {
                int p = wn * 64 + cn * 16 + l16;
                yrow[p] = (f16)((float)yrow[p] + ex * acc[r][cn][reg]);
            }
        }
}

// ---------------- gated rmsnorm: y = rmsnorm(y * silu(z)) * w  (in place) ---
__global__ __launch_bounds__(256) void k_rmsnorm(
    __half* __restrict__ ybuf, const __half* __restrict__ zbuf,
    const float* __restrict__ nw)
{
    int t = threadIdx.x;
    int wv = t >> 6, lane = t & 63;
    long r = (long)blockIdx.x * 4 + wv;
    __half2* yrow = (__half2*)(ybuf + r * 512 + lane * 8);
    const __half2* zrow = (const __half2*)(zbuf + r * 512 + lane * 8);
    float g[8];
#pragma unroll
    for (int j = 0; j < 4; j++) {
        float2 yv = __half22float2(yrow[j]);
        float2 zv = __half22float2(zrow[j]);
        g[2 * j]     = yv.x * siluf(zv.x);
        g[2 * j + 1] = yv.y * siluf(zv.y);
    }
    float ss = 0.f;
#pragma unroll
    for (int i = 0; i < 8; i++) ss += g[i] * g[i];
#pragma unroll
    for (int off = 32; off; off >>= 1) ss += __shfl_xor(ss, off, 64);
    float sc = rsqrtf(ss * (1.0f / 512.0f) + 1e-5f);
#pragma unroll
    for (int j = 0; j < 4; j++) {
        float w0 = nw[lane * 8 + 2 * j], w1 = nw[lane * 8 + 2 * j + 1];
        yrow[j] = __floats2half2_rn(g[2 * j] * sc * w0, g[2 * j + 1] * sc * w1);
    }
}

// ---------------------------------------------------------------------------
extern "C" void kernel_launch(void* const* d_in, const int* in_sizes, int n_in,
                              void* d_out, int out_size, void* d_ws, size_t ws_size,
                              hipStream_t stream)
{
    (void)in_sizes; (void)n_in; (void)out_size; (void)ws_size;
    const float* limg = (const float*)d_in[0];
    const float* rimg = (const float*)d_in[1];
    const float* dsw  = (const float*)d_in[2];
    const float* dsb  = (const float*)d_in[3];
    const float* ipw  = (const float*)d_in[4];
    const float* cw   = (const float*)d_in[5];
    const float* cb   = (const float*)d_in[6];
    const float* dtb  = (const float*)d_in[7];
    const float* alog = (const float*)d_in[8];
    const float* Dv   = (const float*)d_in[9];
    const float* nw   = (const float*)d_in[10];
    const float* opw  = (const float*)d_in[11];
    float* out = (float*)d_out;

    char* ws = (char*)d_ws;
    f16*   F16    = (f16*)  (ws + 0);
    f16*   ipw16  = (f16*)  (ws + 33554432);
    f16*   opw16  = (f16*)  (ws + 34146304);
    float* dtbuf  = (float*)(ws + 34408448);
    float* cumbuf = (float*)(ws + 35457024);
    float* wbuf   = (float*)(ws + 36505600);
    f16*   xT     = (f16*)  (ws + 37554176);
    f16*   XCt    = (f16*)  (ws + 104663040);
    f16*   bcLr   = (f16*)  (ws + 138217472);
    f16*   bcR    = (f16*)  (ws + 146606080);
    f16*   bcL    = (f16*)  (ws + 154994688);
    f16*   ybuf   = (f16*)  (ws + 163383296);
    f16*   states = (f16*)  (ws + 230492160);
    f16*   zbuf   = xT;                          // alias (xT dead after ssd_a)

    const int BIG = 1 << 30;
    k_downsample<<<4096, 256, 0, stream>>>(limg, rimg, dsw, dsb, F16);
    k_cvt<<<1156, 256, 0, stream>>>(ipw, ipw16, 1156 * 256);
    k_cvt<<<512, 256, 0, stream>>>(opw, opw16, 256 * 512);
    // B/C columns (weights rows 1024..1151): out [l][128], split L/R
    k_gemm_mfma<f16><<<dim3(512, 1), 256, 0, stream>>>(
        F16, ipw16 + 1024 * 256, bcLr, bcR, 256, 128, 32768);
    // x columns TRANSPOSED: A=weights rows 512..1023, B=F16 -> xT[512][65536]
    k_gemm_mfma<f16><<<dim3(4, 512), 256, 0, stream>>>(
        ipw16 + 512 * 256, F16, xT, xT, 256, 65536, BIG);
    k_dt<<<16384, 256, 0, stream>>>(F16, ipw, dtb, dtbuf);
    k_cum<<<8, 256, 0, stream>>>(dtbuf, alog, cumbuf, wbuf);
    k_conv_x<<<8192, 256, 0, stream>>>(xT, cw, cb, XCt);
    k_conv_bc<<<16384, 256, 0, stream>>>(bcLr, cw, cb, bcL);
    k_ssd_a<<<2048, 256, 65536, stream>>>(
        xT, XCt, bcR, bcL, dtbuf, cumbuf, wbuf, Dv, ybuf, states);
    k_scan<<<1024, 256, 0, stream>>>(states, cumbuf);
    k_ssd_c<<<2048, 256, 0, stream>>>(bcR, bcL, states, cumbuf, ybuf);
    // z = F @ ipw[0:512]^T (into region freed by xT)
    k_gemm_mfma<f16><<<dim3(512, 4), 256, 0, stream>>>(
        F16, ipw16, zbuf, zbuf, 256, 512, BIG);
    k_rmsnorm<<<16384, 256, 0, stream>>>((__half*)ybuf, (__half*)zbuf, nw);
    // out = y @ opw^T (fp32 out), split L/R halves of d_out
    k_gemm_mfma<float><<<dim3(512, 2), 256, 0, stream>>>(
        ybuf, opw16, out, out + (long)32768 * 256, 512, 256, 32768);
}